// Round 9
// baseline (168.326 us; speedup 1.0000x reference)
//
#include <hip/hip_runtime.h>
#include <math.h>

#define HIDDEN 64
#define SEQ 128
#define BATCH 64
#define NPTS (BATCH * SEQ)   // 8192
#define TMAXV 20.0f
#define L2E 1.4426950408889634f
#define LN2 0.6931471805599453f

typedef float v2f __attribute__((ext_vector_type(2)));

__device__ __forceinline__ float fexp2(float x) { return __builtin_amdgcn_exp2f(x); }
__device__ __forceinline__ float flog2(float x) { return __builtin_amdgcn_logf(x); }
__device__ __forceinline__ float frcp(float x)  { return __builtin_amdgcn_rcpf(x); }
__device__ __forceinline__ float fsigmoid(float x) { return frcp(1.0f + fexp2(-x * L2E)); }
__device__ __forceinline__ float ftanh(float x)    { return 1.0f - 2.0f * frcp(1.0f + fexp2(2.0f * x * L2E)); }

// Raw barrier: orders LDS only (lgkmcnt), does NOT drain vmcnt.
__device__ __forceinline__ void barrier_lds_only() {
    asm volatile("s_waitcnt lgkmcnt(0)" ::: "memory");
    __builtin_amdgcn_s_barrier();
}

// ---- DPP helpers (VALU pipe, no LDS) ----
template <int CTRL>
__device__ __forceinline__ float dpp_mov(float x) {
    int r = __builtin_amdgcn_update_dpp(0, __float_as_int(x), CTRL, 0xf, 0xf, false);
    return __int_as_float(r);
}
// quad_perm(1,0,3,2) = lane^1
__device__ __forceinline__ v2f dpp_xor1_v2(v2f v) {
    v2f r; r.x = dpp_mov<0xB1>(v.x); r.y = dpp_mov<0xB1>(v.y); return r;
}
__device__ __forceinline__ float wave_sum_dpp(float x) {
    x += dpp_mov<0x111>(x);   // row_shr:1
    x += dpp_mov<0x112>(x);   // row_shr:2
    x += dpp_mov<0x114>(x);   // row_shr:4
    x += dpp_mov<0x118>(x);   // row_shr:8  -> lane 16r+15 = row sum
    x += dpp_mov<0x142>(x);   // row_bcast:15
    x += dpp_mov<0x143>(x);   // row_bcast:31 -> lane 63 = total
    return __int_as_float(__builtin_amdgcn_readlane(__float_as_int(x), 63));
}

__device__ __forceinline__ float wave_sum_shfl(float v) {
    v += __shfl_xor(v, 1);  v += __shfl_xor(v, 2);  v += __shfl_xor(v, 4);
    v += __shfl_xor(v, 8);  v += __shfl_xor(v, 16); v += __shfl_xor(v, 32);
    return v;
}

// Blocks [0,64): LSTM rollout, one batch per block, 512 threads.
//   thread = (row r = tid>>1, half p = tid&1). Each thread holds 32 W_hh
//   weights in VGPRs (16 v2f), staged global->LDS->barrier->regs. The staging
//   LDS region ALIASES act_s (overwritten every step), and re-reading would
//   cross per-step s_barriers -> the compiler CANNOT rematerialize the loads;
//   the weights stay register-resident. Per-step weight traffic: ZERO (was
//   64 KB/step/CU = the measured wall in r3/r5/r6).
//   Accumulators map exactly to the old a0..a3 (p=0: a0,a2; p=1: a1,a3);
//   quad-DPP lane^1 adds give (a0+a1)+(a2+a3) -> bit-exact gates; cell/sigma/
//   cum identical per-lane to r3.
// Blocks [64,128): expert-expert MMD term (512-thread version, same per-wave
//   partial sums as before).
__global__ __launch_bounds__(512, 1) void gen_and_ee(
    const float* __restrict__ upool,   // [B,S]
    const float* __restrict__ texp,    // [B,S]
    const float* __restrict__ Wih,     // [256]
    const float* __restrict__ Whh,     // [256,64]
    const float* __restrict__ bih,     // [256]
    const float* __restrict__ bhh,     // [256]
    const float* __restrict__ Vw,      // [64]
    const float* __restrict__ Vb,      // [1]
    float* __restrict__ tl,            // [NPTS] workspace
    float* __restrict__ out)           // [1] loss accumulator
{
    // One aliased pool:
    //   [0, 16384)        floats: weight staging (512 thr x 32 floats)  [LSTM]
    //                     ALSO act_s[2][256] (first 512 floats)         [LSTM]
    //                     ALSO qbuf float2[2048] (first 4096 floats)    [EE]
    //   [16384, 16896)    hx replicas: 8 waves x 64
    //   [16896, 17024)    lu_s[128]
    __shared__ __align__(16) float smem[17056];

    const int bid = blockIdx.x;
    const int tid = threadIdx.x;

    if (bid < BATCH) {
        const int r  = tid >> 1;       // gate row 0..255
        const int p  = tid & 1;        // column half 0/1
        const int l  = tid & 63;       // lane
        const int wv = tid >> 6;       // wave 0..7

        float* stage = smem + tid * 32;
        float* act   = smem;                    // [2][256], aliases staging
        float* hxw   = smem + 16384 + wv * 64;  // this wave's hx replica
        float* lu_s  = smem + 16896;

        // ---- stage this thread's 32 weights into LDS ----
        {
            const float* wrow = Whh + r * 64;
            #pragma unroll
            for (int k = 0; k < 8; ++k) {
                float2 lo = *(const float2*)(wrow + 8 * k + 2 * p);      // cols 8k+2p..+1
                float2 hi = *(const float2*)(wrow + 8 * k + 4 + 2 * p);  // cols 8k+4+2p..+1
                *(float2*)(stage + 2 * k)      = lo;
                *(float2*)(stage + 16 + 2 * k) = hi;
            }
        }
        __syncthreads();

        // ---- read back to registers (non-rematerializable past barriers) ----
        v2f wlo[8], whi[8];
        {
            const float4* s4 = (const float4*)stage;
            #pragma unroll
            for (int m = 0; m < 4; ++m) {
                float4 a = s4[m];        // wlo[2m], wlo[2m+1]
                float4 b = s4[4 + m];    // whi[2m], whi[2m+1]
                wlo[2 * m]     = (v2f){a.x, a.y};
                wlo[2 * m + 1] = (v2f){a.z, a.w};
                whi[2 * m]     = (v2f){b.x, b.y};
                whi[2 * m + 1] = (v2f){b.z, b.w};
            }
        }

        const float bias = bih[r] + bhh[r];
        const float wih  = Wih[r];
        const float vwl  = Vw[l];
        const float vb   = Vb[0];
        const int   gsel = r >> 6;     // 2 -> g-gate (tanh), wave-uniform

        if (tid < SEQ) lu_s[tid] = -flog2(upool[bid * SEQ + tid]) * LN2;
        hxw[l] = 0.0f;                 // every wave zeroes its own replica
        float cx = 0.0f;
        barrier_lds_only();

        // step 0: hx = 0 -> sigma = elu(Vb)+1 (uniform)
        float sg0 = (vb > 0.0f) ? (vb + 1.0f) : fexp2(vb * L2E);
        float cum = lu_s[0] * frcp(sg0);
        float keep = (tid == 0) ? cum : 0.0f;   // thread t keeps cum of step t

        #pragma unroll 1
        for (int s = 0; s < SEQ - 1; ++s) {
            // gate-row partial dot: p=0 accumulates old a0 (alo) & a2 (ahi);
            // p=1 accumulates old a1 & a3. Broadcast b64 reads (2 addrs/instr).
            const v2f* h2 = (const v2f*)hxw;
            v2f alo = {0.f, 0.f}, ahi = {0.f, 0.f};
            #pragma unroll
            for (int k = 0; k < 8; ++k) {
                v2f hlo = h2[4 * k + p];        // cols 8k+2p..+1
                v2f hhi = h2[4 * k + 2 + p];    // cols 8k+4+2p..+1
                alo += wlo[k] * hlo;
                ahi += whi[k] * hhi;
            }
            // cross-half combine: (a0+a1)+(a2+a3), bitwise-exact (add commutes)
            v2f slo = alo + dpp_xor1_v2(alo);
            v2f shi = ahi + dpp_xor1_v2(ahi);
            v2f aa  = slo + shi;
            float g = (aa.x + aa.y) + bias + cum * wih;
            float a = (gsel == 2) ? ftanh(g) : fsigmoid(g);
            if (p == 0) act[(s & 1) * 256 + r] = a;
            barrier_lds_only();        // the ONLY barrier per step

            // redundant cell update in every wave (bit-identical, lane l = h)
            float ig = act[(s & 1) * 256 + l];
            float fg = act[(s & 1) * 256 + 64 + l];
            float gg = act[(s & 1) * 256 + 128 + l];
            float og = act[(s & 1) * 256 + 192 + l];
            cx = fg * cx + ig * gg;
            float hx = og * ftanh(cx);
            hxw[l] = hx;               // own replica; in-wave lgkmcnt ordering

            float tot = wave_sum_dpp(hx * vwl);
            float xx  = tot + vb;
            float sg  = (xx > 0.0f) ? (xx + 1.0f) : fexp2(xx * L2E);
            cum += lu_s[s + 1] * frcp(sg);

            keep = (tid == s + 1) ? cum : keep;
        }
        if (tid < SEQ) tl[bid * SEQ + tid] = keep;
    } else {
        // ---------------- expert-expert MMD term (512-thread) ----------------
        const int eb = bid - BATCH;      // 0..63
        const int pc = eb & 15;          // p-chunk (512 points)
        const int qs = eb >> 4;          // q-split (2048 points)

        float2* qbuf = (float2*)smem;    // [2048]

        const int pp = pc * 512 + tid;
        const float tp = texp[pp];
        const float mp = (tp < TMAXV && tp > 0.0f) ? 1.0f : 0.0f;

        const int q0 = qs * 2048;
        for (int i = tid; i < 2048; i += 512) {
            float tq = texp[q0 + i];
            float mq = (tq < TMAXV && tq > 0.0f) ? 1.0f : 0.0f;
            qbuf[i] = make_float2(tq, mq);
        }
        __syncthreads();

        float acc = 0.0f;
        #pragma unroll 4
        for (int i = 0; i < 2048; ++i) {
            float2 qq = qbuf[i];
            float d = tp - qq.x;
            acc = fmaf(qq.y, fexp2(d * d * (-L2E)), acc);
        }
        acc *= mp;
        acc = wave_sum_shfl(acc);
        if ((tid & 63) == 0) atomicAdd(out, acc);
    }
}

// ll + le terms. Grid (32, 16): 32 p-chunks of 256 x 16 q-splits of 512.
__global__ __launch_bounds__(256) void ll_le(
    const float* __restrict__ texp,
    const float* __restrict__ tl,
    float* __restrict__ out)
{
    __shared__ __align__(16) float4 qbuf[512];
    __shared__ float red[4];

    const int pc = blockIdx.x;
    const int qs = blockIdx.y;
    const int tid = threadIdx.x;

    const int p = pc * 256 + tid;
    const float tlp = tl[p];
    const float mlp = (tlp < TMAXV && tlp > 0.0f) ? 1.0f : 0.0f;

    const int q0 = qs * 512;
    for (int i = tid; i < 512; i += 256) {
        float tq = tl[q0 + i];
        float mq = (tq < TMAXV && tq > 0.0f) ? 1.0f : 0.0f;
        float te = texp[q0 + i];
        float me = (te < TMAXV && te > 0.0f) ? 1.0f : 0.0f;
        qbuf[i] = make_float4(tq, mq, te, me);
    }
    __syncthreads();

    float val = 0.0f;
    // learner times are cumsum of Exp(1) increments: most p-points exceed T_MAX;
    // fully-masked waves skip the whole q-loop (wave-uniform branch).
    if (__ballot(mlp != 0.0f) != 0ULL) {
        float a_ll = 0.0f, a_le = 0.0f;
        #pragma unroll 4
        for (int i = 0; i < 512; ++i) {
            float4 q = qbuf[i];
            float d1 = tlp - q.x;
            a_ll = fmaf(q.y, fexp2(d1 * d1 * (-L2E)), a_ll);
            float d2 = tlp - q.z;
            a_le = fmaf(q.w, fexp2(d2 * d2 * (-L2E)), a_le);
        }
        val = mlp * (a_ll - 2.0f * a_le);
    }

    val = wave_sum_shfl(val);
    if ((tid & 63) == 0) red[tid >> 6] = val;
    __syncthreads();
    if (tid == 0) atomicAdd(out, red[0] + red[1] + red[2] + red[3]);
}

extern "C" void kernel_launch(void* const* d_in, const int* in_sizes, int n_in,
                              void* d_out, int out_size, void* d_ws, size_t ws_size,
                              hipStream_t stream) {
    const float* upool = (const float*)d_in[0];
    const float* texp  = (const float*)d_in[1];
    const float* Wih   = (const float*)d_in[2];
    const float* Whh   = (const float*)d_in[3];
    const float* bih   = (const float*)d_in[4];
    const float* bhh   = (const float*)d_in[5];
    const float* Vw    = (const float*)d_in[6];
    const float* Vb    = (const float*)d_in[7];
    float* out = (float*)d_out;
    float* tl  = (float*)d_ws;   // 8192 floats = 32 KB

    hipMemsetAsync(out, 0, sizeof(float), stream);
    hipLaunchKernelGGL(gen_and_ee, dim3(BATCH + 64), dim3(512), 0, stream,
                       upool, texp, Wih, Whh, bih, bhh, Vw, Vb, tl, out);
    hipLaunchKernelGGL(ll_le, dim3(32, 16), dim3(256), 0, stream, texp, tl, out);
}